// Round 1
// baseline (4907.053 us; speedup 1.0000x reference)
//
#include <hip/hip_runtime.h>
#include <cstdint>
#include <cstddef>

#define N_NODES 20000
#define N_EDGES 320000
#define T_STEPS 12
#define HEADS   4
#define NEG_SLOPE 0.2f

// ---------------- CSR build (dst-sorted), once per call ----------------

__global__ void hist_kernel(const int* __restrict__ dst, int* __restrict__ cnt) {
    int e = blockIdx.x * 256 + threadIdx.x;
    if (e < N_EDGES) atomicAdd(&cnt[dst[e]], 1);
}

__global__ __launch_bounds__(1024) void scan_kernel(const int* __restrict__ cnt,
                                                    int* __restrict__ rp) {
    __shared__ int sd[1024];
    __shared__ int sbase;
    int tid = threadIdx.x;
    if (tid == 0) sbase = 0;
    __syncthreads();
    for (int chunk = 0; chunk < N_NODES; chunk += 1024) {
        int i = chunk + tid;
        int v = (i < N_NODES) ? cnt[i] : 0;
        sd[tid] = v;
        __syncthreads();
        #pragma unroll
        for (int off = 1; off < 1024; off <<= 1) {
            int t = (tid >= off) ? sd[tid - off] : 0;
            __syncthreads();
            sd[tid] += t;
            __syncthreads();
        }
        int incl = sd[tid];
        int base = sbase;
        if (i < N_NODES) rp[i] = base + incl - v;   // exclusive prefix
        __syncthreads();
        if (tid == 1023) sbase = base + incl;
        __syncthreads();
    }
    if (tid == 0) rp[N_NODES] = sbase;              // == N_EDGES
}

__global__ void scatter_kernel(const int* __restrict__ src, const int* __restrict__ dst,
                               const int* __restrict__ rp, int* __restrict__ tmp,
                               int* __restrict__ col) {
    int e = blockIdx.x * 256 + threadIdx.x;
    if (e < N_EDGES) {
        int d = dst[e];
        int pos = rp[d] + atomicAdd(&tmp[d], 1);
        col[pos] = src[e];
    }
}

// ---------------- fp32 tiled GEMM: Y[r, c] = A[r, :] @ W[:, c] ----------------
// A rows are either buf layout [r*K] or x layout [n, t, K] with r = tl*N + n.

__global__ __launch_bounds__(256) void gemm_kernel(
        const float* __restrict__ A, const float* __restrict__ W,
        float* __restrict__ Y, int Mrows, int Ncols, int K,
        int x_layout, int t0) {
    __shared__ float As[16][64];   // [k][m]
    __shared__ float Bs[16][64];   // [k][n]
    int tid = threadIdx.x;
    int tx = tid & 15, ty = tid >> 4;
    int row0 = blockIdx.x * 64;
    int col0 = blockIdx.y * 64;

    float acc[4][4] = {};

    int lrow = tid >> 2;   // 0..63 : A tile row (m)
    int lseg = tid & 3;    // 0..3  : A k-seg (4 floats)
    int brow = tid >> 4;   // 0..15 : B tile row (k)
    int bseg = tid & 15;   // 0..15 : B col-seg (4 floats)

    // precompute A row pointer for this thread's load row
    const float* ap = nullptr;
    int r = row0 + lrow;
    if (r < Mrows) {
        if (x_layout) {
            int tl = r / N_NODES;
            int n  = r - tl * N_NODES;
            ap = A + ((size_t)n * T_STEPS + (size_t)(t0 + tl)) * (size_t)K;
        } else {
            ap = A + (size_t)r * (size_t)K;
        }
    }

    for (int k0 = 0; k0 < K; k0 += 16) {
        float4 av = make_float4(0.f, 0.f, 0.f, 0.f);
        if (ap) av = *(const float4*)(ap + k0 + lseg * 4);
        float4 bv = *(const float4*)(W + (size_t)(k0 + brow) * Ncols + col0 + bseg * 4);

        As[lseg * 4 + 0][lrow] = av.x;
        As[lseg * 4 + 1][lrow] = av.y;
        As[lseg * 4 + 2][lrow] = av.z;
        As[lseg * 4 + 3][lrow] = av.w;
        *(float4*)&Bs[brow][bseg * 4] = bv;
        __syncthreads();

        #pragma unroll
        for (int kk = 0; kk < 16; ++kk) {
            float4 a4 = *(const float4*)&As[kk][ty * 4];
            float4 b4 = *(const float4*)&Bs[kk][tx * 4];
            float a[4] = {a4.x, a4.y, a4.z, a4.w};
            float b[4] = {b4.x, b4.y, b4.z, b4.w};
            #pragma unroll
            for (int i = 0; i < 4; ++i)
                #pragma unroll
                for (int j = 0; j < 4; ++j)
                    acc[i][j] += a[i] * b[j];
        }
        __syncthreads();
    }

    #pragma unroll
    for (int i = 0; i < 4; ++i) {
        int rr = row0 + ty * 4 + i;
        if (rr < Mrows) {
            float4 o = make_float4(acc[i][0], acc[i][1], acc[i][2], acc[i][3]);
            *(float4*)(Y + (size_t)rr * Ncols + col0 + tx * 4) = o;
        }
    }
}

// ---------------- per-node attention logits: alpha_s/alpha_d ----------------
// one 64-lane wave per row r (= tl*N + n); h row length HEADS*C

template <int C>
__global__ __launch_bounds__(64) void alpha_kernel(
        const float* __restrict__ h, const float* __restrict__ a_src,
        const float* __restrict__ a_dst, float* __restrict__ as,
        float* __restrict__ ad) {
    int r = blockIdx.x;
    int lane = threadIdx.x;
    const size_t HC = HEADS * C;
    #pragma unroll
    for (int head = 0; head < HEADS; ++head) {
        float v = (lane < C) ? h[(size_t)r * HC + head * C + lane] : 0.f;
        float s = (lane < C) ? v * a_src[head * C + lane] : 0.f;
        float d = (lane < C) ? v * a_dst[head * C + lane] : 0.f;
        #pragma unroll
        for (int off = 32; off; off >>= 1) {
            s += __shfl_xor(s, off);
            d += __shfl_xor(d, off);
        }
        if (lane == 0) {
            as[(size_t)r * HEADS + head] = s;
            ad[(size_t)r * HEADS + head] = d;
        }
    }
}

// ---------------- edge softmax + aggregation, per (dst node, t) ----------------
// block = 256 threads = 4 waves; wave w handles head w.

template <int C, bool RELU, bool TO_OUT>
__global__ __launch_bounds__(256) void agg_kernel(
        const float* __restrict__ h, const float* __restrict__ as,
        const float* __restrict__ ad, const int* __restrict__ rp,
        const int* __restrict__ col, const float* __restrict__ bias,
        float* __restrict__ out, int t0) {
    int n    = blockIdx.x;
    int tl   = blockIdx.y;
    int head = threadIdx.x >> 6;
    int lane = threadIdx.x & 63;
    const size_t HC = HEADS * C;

    int beg = rp[n], end = rp[n + 1];
    size_t base_t = (size_t)tl * N_NODES;
    float adv = ad[(base_t + n) * HEADS + head];

    // pass 1: per-head max over in-edges (lanes split edges)
    float m = -INFINITY;
    for (int i = beg + lane; i < end; i += 64) {
        int s = col[i];
        float v = as[(base_t + s) * HEADS + head] + adv;
        v = v > 0.f ? v : NEG_SLOPE * v;
        m = fmaxf(m, v);
    }
    #pragma unroll
    for (int off = 32; off; off >>= 1) m = fmaxf(m, __shfl_xor(m, off));

    // pass 2: weighted accumulate (lanes = channels)
    float acc = 0.f, denom = 0.f;
    for (int i = beg; i < end; ++i) {
        int s = col[i];
        float v = as[(base_t + s) * HEADS + head] + adv;
        v = v > 0.f ? v : NEG_SLOPE * v;
        float w = expf(v - m);
        denom += w;
        if (lane < C) acc += w * h[(base_t + s) * HC + head * C + lane];
    }

    if (lane < C) {
        float o = acc / (denom + 1e-16f) + bias[head * C + lane];
        if (RELU) o = fmaxf(o, 0.f);
        if (TO_OUT)
            out[((size_t)n * T_STEPS + (size_t)(t0 + tl)) * HC + head * C + lane] = o;
        else
            out[(base_t + n) * HC + head * C + lane] = o;
    }
}

// ---------------- host ----------------

static inline size_t align256(size_t x) { return (x + 255) & ~(size_t)255; }

extern "C" void kernel_launch(void* const* d_in, const int* in_sizes, int n_in,
                              void* d_out, int out_size, void* d_ws, size_t ws_size,
                              hipStream_t stream) {
    const float* x   = (const float*)d_in[0];
    const int*  eidx = (const int*)d_in[1];
    const float* W1  = (const float*)d_in[2];
    const float* av1 = (const float*)d_in[3];
    const float* aw1 = (const float*)d_in[4];
    const float* b1  = (const float*)d_in[5];
    const float* W2  = (const float*)d_in[6];
    const float* av2 = (const float*)d_in[7];
    const float* aw2 = (const float*)d_in[8];
    const float* b2  = (const float*)d_in[9];
    const float* W3  = (const float*)d_in[10];
    const float* av3 = (const float*)d_in[11];
    const float* aw3 = (const float*)d_in[12];
    const float* b3  = (const float*)d_in[13];
    float* out = (float*)d_out;

    const int* src = eidx;
    const int* dst = eidx + N_EDGES;

    // fixed workspace
    char* p = (char*)d_ws;
    int* rp  = (int*)p; p += align256(sizeof(int) * (N_NODES + 1));
    int* cnt = (int*)p; p += align256(sizeof(int) * N_NODES);
    int* col = (int*)p; p += align256(sizeof(int) * N_EDGES);
    size_t fixed = (size_t)(p - (char*)d_ws);

    // per-timestep chunk sizing
    size_t per_t = align256(sizeof(float) * N_NODES * HEADS) * 2      // alpha_s, alpha_d
                 + align256(sizeof(float) * (size_t)N_NODES * 256) * 2; // h, buf
    int Tc = (int)((ws_size > fixed) ? ((ws_size - fixed) / per_t) : 0);
    if (Tc < 1) Tc = 1;
    if (Tc > T_STEPS) Tc = T_STEPS;

    float* as_b = (float*)p; p += align256(sizeof(float) * (size_t)Tc * N_NODES * HEADS);
    float* ad_b = (float*)p; p += align256(sizeof(float) * (size_t)Tc * N_NODES * HEADS);
    float* hbuf = (float*)p; p += align256(sizeof(float) * (size_t)Tc * N_NODES * 256);
    float* buf  = (float*)p;

    // --- build CSR ---
    hipMemsetAsync(cnt, 0, sizeof(int) * N_NODES, stream);
    hist_kernel<<<(N_EDGES + 255) / 256, 256, 0, stream>>>(dst, cnt);
    scan_kernel<<<1, 1024, 0, stream>>>(cnt, rp);
    hipMemsetAsync(cnt, 0, sizeof(int) * N_NODES, stream);
    scatter_kernel<<<(N_EDGES + 255) / 256, 256, 0, stream>>>(src, dst, rp, cnt, col);

    for (int t0 = 0; t0 < T_STEPS; t0 += Tc) {
        int nT = T_STEPS - t0;
        if (nT > Tc) nT = Tc;
        int Mrows = nT * N_NODES;
        dim3 blk(256);
        dim3 gg1((Mrows + 63) / 64, 256 / 64);
        dim3 ga(N_NODES, nT);

        // layer 1: x -> h (K=128, M=256)
        gemm_kernel<<<gg1, blk, 0, stream>>>(x, W1, hbuf, Mrows, 256, 128, 1, t0);
        alpha_kernel<64><<<Mrows, 64, 0, stream>>>(hbuf, av1, aw1, as_b, ad_b);
        agg_kernel<64, true, false><<<ga, blk, 0, stream>>>(hbuf, as_b, ad_b, rp, col, b1, buf, t0);

        // layer 2: buf -> h (K=256, M=256)
        gemm_kernel<<<gg1, blk, 0, stream>>>(buf, W2, hbuf, Mrows, 256, 256, 0, t0);
        alpha_kernel<64><<<Mrows, 64, 0, stream>>>(hbuf, av2, aw2, as_b, ad_b);
        agg_kernel<64, true, false><<<ga, blk, 0, stream>>>(hbuf, as_b, ad_b, rp, col, b2, buf, t0);

        // layer 3: buf -> h (K=256, M=128), output to d_out
        dim3 gg3((Mrows + 63) / 64, 128 / 64);
        gemm_kernel<<<gg3, blk, 0, stream>>>(buf, W3, hbuf, Mrows, 128, 256, 0, t0);
        alpha_kernel<32><<<Mrows, 64, 0, stream>>>(hbuf, av3, aw3, as_b, ad_b);
        agg_kernel<32, false, true><<<ga, blk, 0, stream>>>(hbuf, as_b, ad_b, rp, col, b3, out, t0);
    }
}

// Round 2
// 3797.187 us; speedup vs baseline: 1.2923x; 1.2923x over previous
//
#include <hip/hip_runtime.h>
#include <cstdint>
#include <cstddef>

#define N_NODES 20000
#define N_EDGES 320000
#define T_STEPS 12
#define HEADS   4
#define NEG_SLOPE 0.2f

// ---------------- CSR build (dst-sorted), once per call ----------------

__global__ void hist_kernel(const int* __restrict__ dst, int* __restrict__ cnt) {
    int e = blockIdx.x * 256 + threadIdx.x;
    if (e < N_EDGES) atomicAdd(&cnt[dst[e]], 1);
}

__global__ __launch_bounds__(1024) void scan_kernel(const int* __restrict__ cnt,
                                                    int* __restrict__ rp) {
    __shared__ int sd[1024];
    __shared__ int sbase;
    int tid = threadIdx.x;
    if (tid == 0) sbase = 0;
    __syncthreads();
    for (int chunk = 0; chunk < N_NODES; chunk += 1024) {
        int i = chunk + tid;
        int v = (i < N_NODES) ? cnt[i] : 0;
        sd[tid] = v;
        __syncthreads();
        #pragma unroll
        for (int off = 1; off < 1024; off <<= 1) {
            int t = (tid >= off) ? sd[tid - off] : 0;
            __syncthreads();
            sd[tid] += t;
            __syncthreads();
        }
        int incl = sd[tid];
        int base = sbase;
        if (i < N_NODES) rp[i] = base + incl - v;   // exclusive prefix
        __syncthreads();
        if (tid == 1023) sbase = base + incl;
        __syncthreads();
    }
    if (tid == 0) rp[N_NODES] = sbase;              // == N_EDGES
}

__global__ void scatter_kernel(const int* __restrict__ src, const int* __restrict__ dst,
                               const int* __restrict__ rp, int* __restrict__ tmp,
                               int* __restrict__ col) {
    int e = blockIdx.x * 256 + threadIdx.x;
    if (e < N_EDGES) {
        int d = dst[e];
        int pos = rp[d] + atomicAdd(&tmp[d], 1);
        col[pos] = src[e];
    }
}

// ---------------- fp32 tiled GEMM: Y[r, :] = A_row(r) @ W ----------------
// Rows are node-major: r = n*nT + tl. A row address = A + (n*strideT + tbase + tl)*K.
// (for buf input: strideT=nT, tbase=0 -> contiguous r*K; for x input: strideT=T_STEPS.)

__global__ __launch_bounds__(256) void gemm_kernel(
        const float* __restrict__ A, const float* __restrict__ W,
        float* __restrict__ Y, int Mrows, int Ncols, int K,
        int strideT, int tbase, int nT) {
    __shared__ float As[16][64];   // [k][m]
    __shared__ float Bs[16][64];   // [k][n]
    int tid = threadIdx.x;
    int tx = tid & 15, ty = tid >> 4;
    int row0 = blockIdx.x * 64;
    int col0 = blockIdx.y * 64;

    float acc[4][4] = {};

    int lrow = tid >> 2;   // 0..63 : A tile row (m)
    int lseg = tid & 3;    // 0..3  : A k-seg (4 floats)
    int brow = tid >> 4;   // 0..15 : B tile row (k)
    int bseg = tid & 15;   // 0..15 : B col-seg (4 floats)

    const float* ap = nullptr;
    int r = row0 + lrow;
    if (r < Mrows) {
        int n  = r / nT;
        int tl = r - n * nT;
        ap = A + ((size_t)n * strideT + (size_t)(tbase + tl)) * (size_t)K;
    }

    for (int k0 = 0; k0 < K; k0 += 16) {
        float4 av = make_float4(0.f, 0.f, 0.f, 0.f);
        if (ap) av = *(const float4*)(ap + k0 + lseg * 4);
        float4 bv = *(const float4*)(W + (size_t)(k0 + brow) * Ncols + col0 + bseg * 4);

        As[lseg * 4 + 0][lrow] = av.x;
        As[lseg * 4 + 1][lrow] = av.y;
        As[lseg * 4 + 2][lrow] = av.z;
        As[lseg * 4 + 3][lrow] = av.w;
        *(float4*)&Bs[brow][bseg * 4] = bv;
        __syncthreads();

        #pragma unroll
        for (int kk = 0; kk < 16; ++kk) {
            float4 a4 = *(const float4*)&As[kk][ty * 4];
            float4 b4 = *(const float4*)&Bs[kk][tx * 4];
            float a[4] = {a4.x, a4.y, a4.z, a4.w};
            float b[4] = {b4.x, b4.y, b4.z, b4.w};
            #pragma unroll
            for (int i = 0; i < 4; ++i)
                #pragma unroll
                for (int j = 0; j < 4; ++j)
                    acc[i][j] += a[i] * b[j];
        }
        __syncthreads();
    }

    #pragma unroll
    for (int i = 0; i < 4; ++i) {
        int rr = row0 + ty * 4 + i;
        if (rr < Mrows) {
            float4 o = make_float4(acc[i][0], acc[i][1], acc[i][2], acc[i][3]);
            *(float4*)(Y + (size_t)rr * Ncols + col0 + tx * 4) = o;
        }
    }
}

// ---------------- per-row attention logits: alpha_s/alpha_d ----------------
// 4 rows per 256-thread block (wave per row).

template <int C>
__global__ __launch_bounds__(256) void alpha_kernel(
        const float* __restrict__ h, const float* __restrict__ a_src,
        const float* __restrict__ a_dst, float* __restrict__ as,
        float* __restrict__ ad, int Mrows) {
    int r = blockIdx.x * 4 + (threadIdx.x >> 6);
    if (r >= Mrows) return;
    int lane = threadIdx.x & 63;
    const int HC = HEADS * C;
    #pragma unroll
    for (int head = 0; head < HEADS; ++head) {
        float v = (lane < C) ? h[(size_t)r * HC + head * C + lane] : 0.f;
        float s = (lane < C) ? v * a_src[head * C + lane] : 0.f;
        float d = (lane < C) ? v * a_dst[head * C + lane] : 0.f;
        #pragma unroll
        for (int off = 32; off; off >>= 1) {
            s += __shfl_xor(s, off);
            d += __shfl_xor(d, off);
        }
        if (lane == 0) {
            as[(size_t)r * HEADS + head] = s;
            ad[(size_t)r * HEADS + head] = d;
        }
    }
}

// ---------------- edge softmax weights (lane-parallel over edges) ----------------
// grid (N_NODES, nT); block 256 = 4 waves (one head each). Writes unnormalized
// w per edge (wbuf[(i*nT+tl)*HEADS+head]) and 1/denom per (row, head).

__global__ __launch_bounds__(256) void softmax_kernel(
        const float* __restrict__ as, const float* __restrict__ ad,
        const int* __restrict__ rp, const int* __restrict__ col,
        float* __restrict__ wbuf, float* __restrict__ invd, int nT) {
    int n = blockIdx.x, tl = blockIdx.y;
    int head = threadIdx.x >> 6, lane = threadIdx.x & 63;
    int beg = rp[n], end = rp[n + 1];
    float adv = ad[((size_t)n * nT + tl) * HEADS + head];

    float m = -INFINITY;
    for (int i = beg + lane; i < end; i += 64) {
        int s = col[i];
        float v = as[((size_t)s * nT + tl) * HEADS + head] + adv;
        v = v > 0.f ? v : NEG_SLOPE * v;
        m = fmaxf(m, v);
    }
    #pragma unroll
    for (int off = 32; off; off >>= 1) m = fmaxf(m, __shfl_xor(m, off));

    float dsum = 0.f;
    for (int i = beg + lane; i < end; i += 64) {
        int s = col[i];
        float v = as[((size_t)s * nT + tl) * HEADS + head] + adv;
        v = v > 0.f ? v : NEG_SLOPE * v;
        float w = expf(v - m);
        dsum += w;
        wbuf[((size_t)i * nT + tl) * HEADS + head] = w;
    }
    #pragma unroll
    for (int off = 32; off; off >>= 1) dsum += __shfl_xor(dsum, off);
    if (lane == 0)
        invd[((size_t)n * nT + tl) * HEADS + head] = 1.f / (dsum + 1e-16f);
}

// ---------------- aggregation: all nT timesteps per edge visit ----------------
// block = HEADS*C threads; thread owns (head, channel); per edge: nT fmas.

template <int NT, int C, bool RELU, bool TO_OUT>
__global__ __launch_bounds__(HEADS * C) void agg_kernel(
        const float* __restrict__ h, const float* __restrict__ wbuf,
        const float* __restrict__ invd, const int* __restrict__ rp,
        const int* __restrict__ col, const float* __restrict__ bias,
        float* __restrict__ out, int t0) {
    constexpr int HC = HEADS * C;
    int n = blockIdx.x;
    int head = threadIdx.x / C;
    int lane = threadIdx.x % C;
    int beg = rp[n], end = rp[n + 1];

    float acc[NT];
    #pragma unroll
    for (int t = 0; t < NT; ++t) acc[t] = 0.f;

    int s_next = (beg < end) ? col[beg] : 0;
    for (int i = beg; i < end; ++i) {
        int s = s_next;
        if (i + 1 < end) s_next = col[i + 1];
        const float* hp = h + (size_t)s * NT * HC + head * C + lane;
        const float* wp = wbuf + (size_t)i * NT * HEADS + head;
        #pragma unroll
        for (int t = 0; t < NT; ++t)
            acc[t] = fmaf(wp[(size_t)t * HEADS], hp[(size_t)t * HC], acc[t]);
    }

    float bv = bias[head * C + lane];
    #pragma unroll
    for (int t = 0; t < NT; ++t) {
        float inv = invd[((size_t)n * NT + t) * HEADS + head];
        float o = acc[t] * inv + bv;
        if (RELU) o = fmaxf(o, 0.f);
        if (TO_OUT)
            out[((size_t)n * T_STEPS + (size_t)(t0 + t)) * HC + head * C + lane] = o;
        else
            out[((size_t)n * NT + t) * HC + head * C + lane] = o;
    }
}

// ---------------- host ----------------

static inline size_t align256(size_t x) { return (x + 255) & ~(size_t)255; }

static size_t need_ws(int tc) {
    size_t s = 0;
    s += align256(sizeof(int) * (N_NODES + 1));
    s += align256(sizeof(int) * N_NODES);
    s += align256(sizeof(int) * N_EDGES);
    s += 3 * align256(4ull * tc * N_NODES * HEADS);        // as, ad, invd
    s += align256(4ull * tc * N_EDGES * HEADS);            // wbuf
    s += 2 * align256(4ull * tc * N_NODES * 256);          // hbuf, buf
    return s;
}

struct Ptrs {
    const float *x, *W1, *av1, *aw1, *b1, *W2, *av2, *aw2, *b2, *W3, *av3, *aw3, *b3;
    float* out;
    int *rp, *col;
    float *as_b, *ad_b, *invd, *wbuf, *hbuf, *buf;
};

template <int NT>
static void run_chunk(const Ptrs& P, int t0, hipStream_t stream) {
    int Mrows = NT * N_NODES;
    dim3 blk(256);
    dim3 gg1((Mrows + 63) / 64, 256 / 64);
    dim3 gg3((Mrows + 63) / 64, 128 / 64);
    dim3 gs(N_NODES, NT);
    int ablocks = (Mrows + 3) / 4;

    // layer 1: x -> h (K=128, out 256)
    gemm_kernel<<<gg1, blk, 0, stream>>>(P.x, P.W1, P.hbuf, Mrows, 256, 128, T_STEPS, t0, NT);
    alpha_kernel<64><<<ablocks, 256, 0, stream>>>(P.hbuf, P.av1, P.aw1, P.as_b, P.ad_b, Mrows);
    softmax_kernel<<<gs, 256, 0, stream>>>(P.as_b, P.ad_b, P.rp, P.col, P.wbuf, P.invd, NT);
    agg_kernel<NT, 64, true, false><<<N_NODES, 256, 0, stream>>>(
        P.hbuf, P.wbuf, P.invd, P.rp, P.col, P.b1, P.buf, t0);

    // layer 2: buf -> h (K=256, out 256)
    gemm_kernel<<<gg1, blk, 0, stream>>>(P.buf, P.W2, P.hbuf, Mrows, 256, 256, NT, 0, NT);
    alpha_kernel<64><<<ablocks, 256, 0, stream>>>(P.hbuf, P.av2, P.aw2, P.as_b, P.ad_b, Mrows);
    softmax_kernel<<<gs, 256, 0, stream>>>(P.as_b, P.ad_b, P.rp, P.col, P.wbuf, P.invd, NT);
    agg_kernel<NT, 64, true, false><<<N_NODES, 256, 0, stream>>>(
        P.hbuf, P.wbuf, P.invd, P.rp, P.col, P.b2, P.buf, t0);

    // layer 3: buf -> h (K=256, out 128) -> d_out
    gemm_kernel<<<gg3, blk, 0, stream>>>(P.buf, P.W3, P.hbuf, Mrows, 128, 256, NT, 0, NT);
    alpha_kernel<32><<<ablocks, 256, 0, stream>>>(P.hbuf, P.av3, P.aw3, P.as_b, P.ad_b, Mrows);
    softmax_kernel<<<gs, 256, 0, stream>>>(P.as_b, P.ad_b, P.rp, P.col, P.wbuf, P.invd, NT);
    agg_kernel<NT, 32, false, true><<<N_NODES, 128, 0, stream>>>(
        P.hbuf, P.wbuf, P.invd, P.rp, P.col, P.b3, P.out, t0);
}

extern "C" void kernel_launch(void* const* d_in, const int* in_sizes, int n_in,
                              void* d_out, int out_size, void* d_ws, size_t ws_size,
                              hipStream_t stream) {
    Ptrs P;
    P.x   = (const float*)d_in[0];
    const int* eidx = (const int*)d_in[1];
    P.W1 = (const float*)d_in[2];  P.av1 = (const float*)d_in[3];
    P.aw1 = (const float*)d_in[4]; P.b1 = (const float*)d_in[5];
    P.W2 = (const float*)d_in[6];  P.av2 = (const float*)d_in[7];
    P.aw2 = (const float*)d_in[8]; P.b2 = (const float*)d_in[9];
    P.W3 = (const float*)d_in[10]; P.av3 = (const float*)d_in[11];
    P.aw3 = (const float*)d_in[12]; P.b3 = (const float*)d_in[13];
    P.out = (float*)d_out;

    const int* src = eidx;
    const int* dst = eidx + N_EDGES;

    // pick largest chunk (divisor of 12) that fits in ws
    int Tc = 1;
    const int cands[6] = {12, 6, 4, 3, 2, 1};
    for (int k = 0; k < 6; ++k) {
        if (need_ws(cands[k]) <= ws_size) { Tc = cands[k]; break; }
    }

    char* p = (char*)d_ws;
    P.rp  = (int*)p; p += align256(sizeof(int) * (N_NODES + 1));
    int* cnt = (int*)p; p += align256(sizeof(int) * N_NODES);
    P.col = (int*)p; p += align256(sizeof(int) * N_EDGES);
    P.as_b = (float*)p; p += align256(4ull * Tc * N_NODES * HEADS);
    P.ad_b = (float*)p; p += align256(4ull * Tc * N_NODES * HEADS);
    P.invd = (float*)p; p += align256(4ull * Tc * N_NODES * HEADS);
    P.wbuf = (float*)p; p += align256(4ull * Tc * N_EDGES * HEADS);
    P.hbuf = (float*)p; p += align256(4ull * Tc * N_NODES * 256);
    P.buf  = (float*)p;

    // --- build CSR (deterministic per call; edge order within node may vary,
    // fp sums stay well within threshold) ---
    hipMemsetAsync(cnt, 0, sizeof(int) * N_NODES, stream);
    hist_kernel<<<(N_EDGES + 255) / 256, 256, 0, stream>>>(dst, cnt);
    scan_kernel<<<1, 1024, 0, stream>>>(cnt, P.rp);
    hipMemsetAsync(cnt, 0, sizeof(int) * N_NODES, stream);
    scatter_kernel<<<(N_EDGES + 255) / 256, 256, 0, stream>>>(src, dst, P.rp, cnt, P.col);

    for (int t0 = 0; t0 < T_STEPS; t0 += Tc) {
        switch (Tc) {
            case 12: run_chunk<12>(P, t0, stream); break;
            case 6:  run_chunk<6>(P, t0, stream); break;
            case 4:  run_chunk<4>(P, t0, stream); break;
            case 3:  run_chunk<3>(P, t0, stream); break;
            case 2:  run_chunk<2>(P, t0, stream); break;
            default: run_chunk<1>(P, t0, stream); break;
        }
    }
}

// Round 3
// 2797.148 us; speedup vs baseline: 1.7543x; 1.3575x over previous
//
#include <hip/hip_runtime.h>
#include <cstdint>
#include <cstddef>

#define N_NODES 20000
#define N_EDGES 320000
#define T_STEPS 12
#define HEADS   4
#define NEG_SLOPE 0.2f

// ---------------- CSR build (dst-sorted), once per call ----------------

__global__ void hist_kernel(const int* __restrict__ dst, int* __restrict__ cnt) {
    int e = blockIdx.x * 256 + threadIdx.x;
    if (e < N_EDGES) atomicAdd(&cnt[dst[e]], 1);
}

__global__ __launch_bounds__(1024) void scan_kernel(const int* __restrict__ cnt,
                                                    int* __restrict__ rp) {
    __shared__ int sd[1024];
    __shared__ int sbase;
    int tid = threadIdx.x;
    if (tid == 0) sbase = 0;
    __syncthreads();
    for (int chunk = 0; chunk < N_NODES; chunk += 1024) {
        int i = chunk + tid;
        int v = (i < N_NODES) ? cnt[i] : 0;
        sd[tid] = v;
        __syncthreads();
        #pragma unroll
        for (int off = 1; off < 1024; off <<= 1) {
            int t = (tid >= off) ? sd[tid - off] : 0;
            __syncthreads();
            sd[tid] += t;
            __syncthreads();
        }
        int incl = sd[tid];
        int base = sbase;
        if (i < N_NODES) rp[i] = base + incl - v;   // exclusive prefix
        __syncthreads();
        if (tid == 1023) sbase = base + incl;
        __syncthreads();
    }
    if (tid == 0) rp[N_NODES] = sbase;              // == N_EDGES
}

__global__ void scatter_kernel(const int* __restrict__ src, const int* __restrict__ dst,
                               const int* __restrict__ rp, int* __restrict__ tmp,
                               int* __restrict__ col) {
    int e = blockIdx.x * 256 + threadIdx.x;
    if (e < N_EDGES) {
        int d = dst[e];
        int pos = rp[d] + atomicAdd(&tmp[d], 1);
        col[pos] = src[e];
    }
}

// ---------------- fp32 GEMM, 128x128 tile, 8x8 per thread ----------------
// Fragments split 2x2 of 4x4 so every LDS access is <=2-way banked.
// Row r maps to A + (n*strideT + tbase + tl)*K, n=r/nT, tl=r%nT.

__global__ __launch_bounds__(256) void gemm_kernel(
        const float* __restrict__ A, const float* __restrict__ W,
        float* __restrict__ Y, int Mrows, int Ncols, int K,
        int strideT, int tbase, int nT) {
    __shared__ float As[16][132];
    __shared__ float Bs[16][132];
    int tid = threadIdx.x;
    int tx = tid & 15, ty = tid >> 4;
    int row0 = blockIdx.x * 128;
    int col0 = blockIdx.y * 128;

    float acc[2][2][4][4] = {};

    // A staging: row m = tid>>1 (0..127), k-seg = (tid&1)*8
    int am = tid >> 1;
    int ak = (tid & 1) * 8;
    const float* ap = nullptr;
    {
        int r = row0 + am;
        if (r < Mrows) {
            int n = r / nT, tl = r - n * nT;
            ap = A + ((size_t)n * strideT + (size_t)(tbase + tl)) * (size_t)K + ak;
        }
    }
    // B staging: k = tid>>4 (0..15), col-seg = (tid&15)*8
    int bk = tid >> 4;
    int bc = (tid & 15) * 8;
    const float* bp = W + (size_t)bk * Ncols + col0 + bc;

    for (int k0 = 0; k0 < K; k0 += 16) {
        float4 a0 = make_float4(0.f, 0.f, 0.f, 0.f), a1 = a0;
        if (ap) {
            a0 = *(const float4*)(ap + k0);
            a1 = *(const float4*)(ap + k0 + 4);
        }
        float4 b0 = *(const float4*)(bp + (size_t)k0 * Ncols);
        float4 b1 = *(const float4*)(bp + (size_t)k0 * Ncols + 4);

        As[ak + 0][am] = a0.x; As[ak + 1][am] = a0.y;
        As[ak + 2][am] = a0.z; As[ak + 3][am] = a0.w;
        As[ak + 4][am] = a1.x; As[ak + 5][am] = a1.y;
        As[ak + 6][am] = a1.z; As[ak + 7][am] = a1.w;
        *(float4*)&Bs[bk][bc] = b0;
        *(float4*)&Bs[bk][bc + 4] = b1;
        __syncthreads();

        #pragma unroll
        for (int kk = 0; kk < 16; ++kk) {
            float4 aA = *(const float4*)&As[kk][ty * 4];
            float4 aB = *(const float4*)&As[kk][64 + ty * 4];
            float4 bA = *(const float4*)&Bs[kk][tx * 4];
            float4 bB = *(const float4*)&Bs[kk][64 + tx * 4];
            float am_[2][4] = {{aA.x, aA.y, aA.z, aA.w}, {aB.x, aB.y, aB.z, aB.w}};
            float bm_[2][4] = {{bA.x, bA.y, bA.z, bA.w}, {bB.x, bB.y, bB.z, bB.w}};
            #pragma unroll
            for (int mh = 0; mh < 2; ++mh)
                #pragma unroll
                for (int nh = 0; nh < 2; ++nh)
                    #pragma unroll
                    for (int i = 0; i < 4; ++i)
                        #pragma unroll
                        for (int j = 0; j < 4; ++j)
                            acc[mh][nh][i][j] = fmaf(am_[mh][i], bm_[nh][j], acc[mh][nh][i][j]);
        }
        __syncthreads();
    }

    #pragma unroll
    for (int mh = 0; mh < 2; ++mh)
        #pragma unroll
        for (int i = 0; i < 4; ++i) {
            int rr = row0 + mh * 64 + ty * 4 + i;
            if (rr < Mrows) {
                float4 o0 = make_float4(acc[mh][0][i][0], acc[mh][0][i][1],
                                        acc[mh][0][i][2], acc[mh][0][i][3]);
                float4 o1 = make_float4(acc[mh][1][i][0], acc[mh][1][i][1],
                                        acc[mh][1][i][2], acc[mh][1][i][3]);
                *(float4*)(Y + (size_t)rr * Ncols + col0 + tx * 4) = o0;
                *(float4*)(Y + (size_t)rr * Ncols + col0 + 64 + tx * 4) = o1;
            }
        }
}

// ---------------- per-row attention logits: alpha_s/alpha_d ----------------

template <int C>
__global__ __launch_bounds__(256) void alpha_kernel(
        const float* __restrict__ h, const float* __restrict__ a_src,
        const float* __restrict__ a_dst, float* __restrict__ as,
        float* __restrict__ ad, int Mrows) {
    int r = blockIdx.x * 4 + (threadIdx.x >> 6);
    if (r >= Mrows) return;
    int lane = threadIdx.x & 63;
    const int HC = HEADS * C;
    #pragma unroll
    for (int head = 0; head < HEADS; ++head) {
        float v = (lane < C) ? h[(size_t)r * HC + head * C + lane] : 0.f;
        float s = (lane < C) ? v * a_src[head * C + lane] : 0.f;
        float d = (lane < C) ? v * a_dst[head * C + lane] : 0.f;
        #pragma unroll
        for (int off = 32; off; off >>= 1) {
            s += __shfl_xor(s, off);
            d += __shfl_xor(d, off);
        }
        if (lane == 0) {
            as[(size_t)r * HEADS + head] = s;
            ad[(size_t)r * HEADS + head] = d;
        }
    }
}

// ---------------- fused softmax + aggregation ----------------
// grid (N_NODES, NTOT/NT). Block = HEADS*C threads.
// Phase A (per edge chunk): edge-parallel w = exp(leaky(as+ad) - max) -> LDS.
// Phase B: thread (head, c) accumulates NT timesteps per edge visit.

template <int NTOT, int NT, int C, bool RELU, bool TO_OUT>
__global__ __launch_bounds__(HEADS * C) void agg_kernel(
        const float* __restrict__ h, const float* __restrict__ as,
        const float* __restrict__ ad, const int* __restrict__ rp,
        const int* __restrict__ col, const float* __restrict__ bias,
        float* __restrict__ out, int t0) {
    constexpr int HC  = HEADS * C;
    constexpr int NW  = HC / 64;       // waves per block
    constexpr int HPW = HEADS / NW;    // heads per wave in phase A
    constexpr int CHUNK = 64;
    constexpr int WSTR = 25;           // padded stride (NT*HEADS<=24), odd -> 2-way max

    __shared__ int   s_col[CHUNK];
    __shared__ float s_w[CHUNK][WSTR];
    __shared__ float s_inv[NT][HEADS];

    int n = blockIdx.x;
    int tbase = blockIdx.y * NT;
    int tid = threadIdx.x;
    int wave = tid >> 6, lane = tid & 63;

    int beg = rp[n], end = rp[n + 1];

    float mx[HPW][NT], dsum[HPW][NT], adv[HPW][NT];
    #pragma unroll
    for (int hp = 0; hp < HPW; ++hp) {
        int head = wave + hp * NW;
        #pragma unroll
        for (int t = 0; t < NT; ++t) {
            mx[hp][t] = -INFINITY;
            dsum[hp][t] = 0.f;
            adv[hp][t] = ad[((size_t)n * NTOT + tbase + t) * HEADS + head];
        }
    }

    // pass 0: global max per (head, t)
    for (int i = beg + lane; i < end; i += 64) {
        int s = col[i];
        #pragma unroll
        for (int hp = 0; hp < HPW; ++hp) {
            int head = wave + hp * NW;
            #pragma unroll
            for (int t = 0; t < NT; ++t) {
                float v = as[((size_t)s * NTOT + tbase + t) * HEADS + head] + adv[hp][t];
                v = v > 0.f ? v : NEG_SLOPE * v;
                mx[hp][t] = fmaxf(mx[hp][t], v);
            }
        }
    }
    #pragma unroll
    for (int off = 32; off; off >>= 1)
        #pragma unroll
        for (int hp = 0; hp < HPW; ++hp)
            #pragma unroll
            for (int t = 0; t < NT; ++t)
                mx[hp][t] = fmaxf(mx[hp][t], __shfl_xor(mx[hp][t], off));

    int head_b = tid / C;
    int c_b = tid % C;
    float acc[NT];
    #pragma unroll
    for (int t = 0; t < NT; ++t) acc[t] = 0.f;

    for (int c0 = beg; c0 < end; c0 += CHUNK) {
        int cnt = min(CHUNK, end - c0);
        if (tid < cnt) s_col[tid] = col[c0 + tid];
        __syncthreads();
        // phase A: compute edge weights into LDS (one exp per (e,t,head))
        if (lane < cnt) {
            int s = s_col[lane];
            #pragma unroll
            for (int hp = 0; hp < HPW; ++hp) {
                int head = wave + hp * NW;
                #pragma unroll
                for (int t = 0; t < NT; ++t) {
                    float v = as[((size_t)s * NTOT + tbase + t) * HEADS + head] + adv[hp][t];
                    v = v > 0.f ? v : NEG_SLOPE * v;
                    float w = __expf(v - mx[hp][t]);
                    dsum[hp][t] += w;
                    s_w[lane][t * HEADS + head] = w;
                }
            }
        }
        __syncthreads();
        // phase B: weighted gather-accumulate
        for (int e = 0; e < cnt; ++e) {
            int s = s_col[e];
            const float* hp_ = h + ((size_t)s * NTOT + tbase) * HC + head_b * C + c_b;
            #pragma unroll
            for (int t = 0; t < NT; ++t)
                acc[t] = fmaf(s_w[e][t * HEADS + head_b], hp_[(size_t)t * HC], acc[t]);
        }
        __syncthreads();
    }

    #pragma unroll
    for (int off = 32; off; off >>= 1)
        #pragma unroll
        for (int hp = 0; hp < HPW; ++hp)
            #pragma unroll
            for (int t = 0; t < NT; ++t)
                dsum[hp][t] += __shfl_xor(dsum[hp][t], off);
    if (lane == 0) {
        #pragma unroll
        for (int hp = 0; hp < HPW; ++hp)
            #pragma unroll
            for (int t = 0; t < NT; ++t)
                s_inv[t][wave + hp * NW] = 1.f / (dsum[hp][t] + 1e-16f);
    }
    __syncthreads();

    float bv = bias[head_b * C + c_b];
    #pragma unroll
    for (int t = 0; t < NT; ++t) {
        float o = acc[t] * s_inv[t][head_b] + bv;
        if (RELU) o = fmaxf(o, 0.f);
        if (TO_OUT)
            out[((size_t)n * T_STEPS + (size_t)(t0 + tbase + t)) * HC + head_b * C + c_b] = o;
        else
            out[((size_t)n * NTOT + tbase + t) * HC + head_b * C + c_b] = o;
    }
}

// ---------------- host ----------------

static inline size_t align256(size_t x) { return (x + 255) & ~(size_t)255; }

static size_t need_ws(int tc) {
    size_t s = 0;
    s += align256(sizeof(int) * (N_NODES + 1));
    s += align256(sizeof(int) * N_NODES);
    s += align256(sizeof(int) * N_EDGES);
    s += 2 * align256(4ull * tc * N_NODES * HEADS);        // as, ad
    s += 2 * align256(4ull * tc * N_NODES * 256);          // hbuf, buf
    return s;
}

struct Ptrs {
    const float *x, *W1, *av1, *aw1, *b1, *W2, *av2, *aw2, *b2, *W3, *av3, *aw3, *b3;
    float* out;
    int *rp, *col;
    float *as_b, *ad_b, *hbuf, *buf;
};

template <int NTOT>
static void run_chunk(const Ptrs& P, int t0, hipStream_t stream) {
    constexpr int NTA  = (NTOT % 2 == 0 && NTOT > 4) ? NTOT / 2 : NTOT;  // t-split for L3 fit
    constexpr int NSPL = NTOT / NTA;
    int Mrows = NTOT * N_NODES;
    dim3 gg1((Mrows + 127) / 128, 256 / 128);
    dim3 gg3((Mrows + 127) / 128, 128 / 128);
    dim3 ga(N_NODES, NSPL);
    int ablocks = (Mrows + 3) / 4;

    // layer 1: x -> h (K=128, out 256)
    gemm_kernel<<<gg1, 256, 0, stream>>>(P.x, P.W1, P.hbuf, Mrows, 256, 128, T_STEPS, t0, NTOT);
    alpha_kernel<64><<<ablocks, 256, 0, stream>>>(P.hbuf, P.av1, P.aw1, P.as_b, P.ad_b, Mrows);
    agg_kernel<NTOT, NTA, 64, true, false><<<ga, 256, 0, stream>>>(
        P.hbuf, P.as_b, P.ad_b, P.rp, P.col, P.b1, P.buf, t0);

    // layer 2: buf -> h (K=256, out 256)
    gemm_kernel<<<gg1, 256, 0, stream>>>(P.buf, P.W2, P.hbuf, Mrows, 256, 256, NTOT, 0, NTOT);
    alpha_kernel<64><<<ablocks, 256, 0, stream>>>(P.hbuf, P.av2, P.aw2, P.as_b, P.ad_b, Mrows);
    agg_kernel<NTOT, NTA, 64, true, false><<<ga, 256, 0, stream>>>(
        P.hbuf, P.as_b, P.ad_b, P.rp, P.col, P.b2, P.buf, t0);

    // layer 3: buf -> h (K=256, out 128) -> d_out
    gemm_kernel<<<gg3, 256, 0, stream>>>(P.buf, P.W3, P.hbuf, Mrows, 128, 256, NTOT, 0, NTOT);
    alpha_kernel<32><<<ablocks, 256, 0, stream>>>(P.hbuf, P.av3, P.aw3, P.as_b, P.ad_b, Mrows);
    agg_kernel<NTOT, NTA, 32, false, true><<<ga, 128, 0, stream>>>(
        P.hbuf, P.as_b, P.ad_b, P.rp, P.col, P.b3, P.out, t0);
}

extern "C" void kernel_launch(void* const* d_in, const int* in_sizes, int n_in,
                              void* d_out, int out_size, void* d_ws, size_t ws_size,
                              hipStream_t stream) {
    Ptrs P;
    P.x   = (const float*)d_in[0];
    const int* eidx = (const int*)d_in[1];
    P.W1 = (const float*)d_in[2];  P.av1 = (const float*)d_in[3];
    P.aw1 = (const float*)d_in[4]; P.b1 = (const float*)d_in[5];
    P.W2 = (const float*)d_in[6];  P.av2 = (const float*)d_in[7];
    P.aw2 = (const float*)d_in[8]; P.b2 = (const float*)d_in[9];
    P.W3 = (const float*)d_in[10]; P.av3 = (const float*)d_in[11];
    P.aw3 = (const float*)d_in[12]; P.b3 = (const float*)d_in[13];
    P.out = (float*)d_out;

    const int* src = eidx;
    const int* dst = eidx + N_EDGES;

    int Tc = 1;
    const int cands[6] = {12, 6, 4, 3, 2, 1};
    for (int k = 0; k < 6; ++k) {
        if (need_ws(cands[k]) <= ws_size) { Tc = cands[k]; break; }
    }

    char* p = (char*)d_ws;
    P.rp  = (int*)p; p += align256(sizeof(int) * (N_NODES + 1));
    int* cnt = (int*)p; p += align256(sizeof(int) * N_NODES);
    P.col = (int*)p; p += align256(sizeof(int) * N_EDGES);
    P.as_b = (float*)p; p += align256(4ull * Tc * N_NODES * HEADS);
    P.ad_b = (float*)p; p += align256(4ull * Tc * N_NODES * HEADS);
    P.hbuf = (float*)p; p += align256(4ull * Tc * N_NODES * 256);
    P.buf  = (float*)p;

    // --- build CSR ---
    hipMemsetAsync(cnt, 0, sizeof(int) * N_NODES, stream);
    hist_kernel<<<(N_EDGES + 255) / 256, 256, 0, stream>>>(dst, cnt);
    scan_kernel<<<1, 1024, 0, stream>>>(cnt, P.rp);
    hipMemsetAsync(cnt, 0, sizeof(int) * N_NODES, stream);
    scatter_kernel<<<(N_EDGES + 255) / 256, 256, 0, stream>>>(src, dst, P.rp, cnt, P.col);

    for (int t0 = 0; t0 < T_STEPS; t0 += Tc) {
        switch (Tc) {
            case 12: run_chunk<12>(P, t0, stream); break;
            case 6:  run_chunk<6>(P, t0, stream); break;
            case 4:  run_chunk<4>(P, t0, stream); break;
            case 3:  run_chunk<3>(P, t0, stream); break;
            case 2:  run_chunk<2>(P, t0, stream); break;
            default: run_chunk<1>(P, t0, stream); break;
        }
    }
}